// Round 7
// baseline (2015.560 us; speedup 1.0000x reference)
//
#include <hip/hip_runtime.h>
#include <cstdio>

typedef unsigned short u16;
typedef float f32x4 __attribute__((ext_vector_type(4)));
typedef short s16x8 __attribute__((ext_vector_type(8)));

__device__ __forceinline__ u16 f2bf(float x) {
    unsigned u = __float_as_uint(x);
    u += 0x7fffu + ((u >> 16) & 1u);
    return (u16)(u >> 16);
}
__device__ __forceinline__ unsigned pack2(float a, float b) {
    return (unsigned)f2bf(a) | ((unsigned)f2bf(b) << 16);
}
__device__ __forceinline__ void unpack2(unsigned u, float& lo, float& hi) {
    lo = __uint_as_float(u << 16);
    hi = __uint_as_float(u & 0xffff0000u);
}

// async global->LDS, 16B per lane; LDS dest must be wave-uniform base + lane*16
__device__ __forceinline__ void gl2lds16(const u16* g, u16* l) {
    __builtin_amdgcn_global_load_lds(
        (const __attribute__((address_space(1))) void*)g,
        (__attribute__((address_space(3))) void*)l, 16, 0, 0);
}

// ---------------- fused one-time weight cast (7 tensors -> 80 MiB bf16) -----
__global__ __launch_bounds__(256) void cast_w7(
    const float* __restrict__ p0, const float* __restrict__ p1,
    const float* __restrict__ p2, const float* __restrict__ p3,
    const float* __restrict__ p4, const float* __restrict__ p5,
    const float* __restrict__ p6, u16* __restrict__ dst) {
    long i = (long)blockIdx.x * 256 + threadIdx.x;  // float4 index
    if (i >= 10485760L) return;
    const float* src;
    long base;
    if (i < 3145728L)      { src = p0; base = 0L; }
    else if (i < 6291456L) { src = p1; base = 3145728L; }
    else if (i < 7340032L) { src = p2; base = 6291456L; }
    else if (i < 8388608L) { src = p3; base = 7340032L; }
    else if (i < 9437184L) { src = p4; base = 8388608L; }
    else if (i < 9961472L) { src = p5; base = 9437184L; }
    else                   { src = p6; base = 9961472L; }
    float4 v = ((const float4*)src)[i - base];
    uint2 r;
    r.x = pack2(v.x, v.y);
    r.y = pack2(v.z, v.w);
    ((uint2*)dst)[i] = r;
}

// ---------------- fused per-chunk input cast (text + graph) -----------------
__global__ __launch_bounds__(256) void cast_in(const float* __restrict__ t,
                                               const float* __restrict__ g,
                                               u16* __restrict__ yt,
                                               u16* __restrict__ yg,
                                               int nt4, int ng4) {
    int i = blockIdx.x * 256 + threadIdx.x;
    const float* src;
    u16* dst;
    int idx;
    if (i < nt4) {
        src = t; dst = yt; idx = i;
    } else {
        idx = i - nt4;
        if (idx >= ng4) return;
        src = g; dst = yg;
    }
    float4 v = ((const float4*)src)[idx];
    uint2 r;
    r.x = pack2(v.x, v.y);
    r.y = pack2(v.z, v.w);
    ((uint2*)dst)[idx] = r;
}

// ---------------- async-staged GEMM (bf16 A w/ stride, bf16 B dense) --------
// m97 structure kept for small-N shapes (S9). 128x128 tile, BK=32.
template <bool OUT_BF16>
__global__ __launch_bounds__(256) void gemm_async(const u16* __restrict__ A, int lda,
                                                  const u16* __restrict__ B,
                                                  const float* __restrict__ bias,
                                                  void* __restrict__ Cout,
                                                  int K, int ldc) {
    __shared__ __align__(16) u16 As[128 * 32];
    __shared__ __align__(16) u16 Bs[128 * 32];

    const int tid = threadIdx.x;
    const int lane = tid & 63;
    const int wave = tid >> 6;
    const int wm = wave >> 1;
    const int wn = wave & 1;
    const size_t bm = (size_t)blockIdx.y * 128;
    const size_t bn = (size_t)blockIdx.x * 128;

    f32x4 acc[4][4];
#pragma unroll
    for (int i = 0; i < 4; ++i)
#pragma unroll
        for (int j = 0; j < 4; ++j) acc[i][j] = (f32x4)0.f;

    const int srow = tid >> 2;        // 0..63
    const int scol = (tid & 3) << 3;  // 0,8,16,24
    const u16* Ag = A + (bm + (size_t)srow) * (size_t)lda + scol;
    const u16* Bg = B + (bn + (size_t)srow) * (size_t)K + scol;
    const size_t rA = (size_t)64 * lda;
    const size_t rB = (size_t)64 * K;
    u16* lA0 = &As[tid * 8];
    u16* lA1 = &As[2048 + tid * 8];
    u16* lB0 = &Bs[tid * 8];
    u16* lB1 = &Bs[2048 + tid * 8];

    const int lrow = lane & 15;
    const int lk = (lane >> 4) << 3;

    const int niter = K >> 5;
    for (int t = 0; t < niter; ++t) {
        __syncthreads();
        gl2lds16(Ag, lA0);
        gl2lds16(Ag + rA, lA1);
        gl2lds16(Bg, lB0);
        gl2lds16(Bg + rB, lB1);
        Ag += 32;
        Bg += 32;
        __syncthreads();
        s16x8 af[4], bfr[4];
#pragma unroll
        for (int i = 0; i < 4; ++i)
            af[i] = *(const s16x8*)&As[(wm * 64 + i * 16 + lrow) * 32 + lk];
#pragma unroll
        for (int j = 0; j < 4; ++j)
            bfr[j] = *(const s16x8*)&Bs[(wn * 64 + j * 16 + lrow) * 32 + lk];
#pragma unroll
        for (int i = 0; i < 4; ++i)
#pragma unroll
            for (int j = 0; j < 4; ++j)
                acc[i][j] = __builtin_amdgcn_mfma_f32_16x16x32_bf16(
                    af[i], bfr[j], acc[i][j], 0, 0, 0);
    }

    const size_t crow0 = bm + wm * 64 + ((lane >> 4) << 2);
    const int ccol0 = (int)bn + wn * 64 + (lane & 15);
#pragma unroll
    for (int i = 0; i < 4; ++i) {
#pragma unroll
        for (int j = 0; j < 4; ++j) {
            const int col = ccol0 + j * 16;
            const float bv = bias[col];
            const size_t base = (crow0 + (size_t)i * 16) * (size_t)ldc + col;
#pragma unroll
            for (int r = 0; r < 4; ++r) {
                const float v = acc[i][j][r] + bv;
                if (OUT_BF16)
                    ((u16*)Cout)[base + (size_t)r * ldc] = f2bf(v);
                else
                    ((float*)Cout)[base + (size_t)r * ldc] = v;
            }
        }
    }
}

// ---------------- 256x256 4-window GEMM with read/MFMA overlap --------------
// (R5 schedule restored — best measured: 210 µs. R6 single-buffer regressed:
// occupancy can't rise past 1 blk/CU anyway because acc=128 AGPR/wave caps
// waves at 2/SIMD; and its steady-loop vmcnt(0) serialized staging.)
// NEW vs R5: column-major block mapping — an XCD's chunk of consecutive wg
// runs 32 bm-tiles at FIXED bn, so the 1 MB B-panel stays L2-resident
// (row-major swept all B panels: 24 MB >> 4 MB L2 -> 5.7x HBM over-fetch).
#define STG_A02(v)                                                            \
    do {                                                                      \
        gl2lds16(aG + (size_t)(v) * 64, &As[(v) & 1][tid * 8]);               \
        gl2lds16(aG + 2 * a64 + (size_t)(v) * 64,                             \
                 &As[(v) & 1][8192 + tid * 8]);                               \
    } while (0)
#define STG_A13(v)                                                            \
    do {                                                                      \
        gl2lds16(aG + a64 + (size_t)(v) * 64, &As[(v) & 1][4096 + tid * 8]);  \
        gl2lds16(aG + 3 * a64 + (size_t)(v) * 64,                             \
                 &As[(v) & 1][12288 + tid * 8]);                              \
    } while (0)
#define STG_B01(v)                                                            \
    do {                                                                      \
        gl2lds16(bG + (size_t)(v) * 64, &Bs[(v) & 1][tid * 8]);               \
        gl2lds16(bG + b64 + (size_t)(v) * 64, &Bs[(v) & 1][4096 + tid * 8]);  \
    } while (0)
#define STG_B23(v)                                                            \
    do {                                                                      \
        gl2lds16(bG + 2 * b64 + (size_t)(v) * 64,                             \
                 &Bs[(v) & 1][8192 + tid * 8]);                               \
        gl2lds16(bG + 3 * b64 + (size_t)(v) * 64,                             \
                 &Bs[(v) & 1][12288 + tid * 8]);                              \
    } while (0)
#define RD_AF(buf, mh, m)                                                     \
    do {                                                                      \
        const u16* p_ = &As[buf][aRow + ((mh) * 64 + (m) * 16) * 64];         \
        aF[m][0] = *(const s16x8*)(p_ + aK0);                                 \
        aF[m][1] = *(const s16x8*)(p_ + aK1);                                 \
    } while (0)
#define RD_B(buf, nh, dst)                                                    \
    do {                                                                      \
        _Pragma("unroll") for (int n_ = 0; n_ < 2; ++n_) {                    \
            const u16* p_ = &Bs[buf][bRow + ((nh) * 32 + n_ * 16) * 64];      \
            dst[n_][0] = *(const s16x8*)(p_ + aK0);                           \
            dst[n_][1] = *(const s16x8*)(p_ + aK1);                           \
        }                                                                     \
    } while (0)
#define MFMA4(ar, bv, ci, cj)                                                 \
    do {                                                                      \
        acc[ci][cj] = __builtin_amdgcn_mfma_f32_16x16x32_bf16(                \
            (ar)[0], (bv)[0], acc[ci][cj], 0, 0, 0);                          \
        acc[ci][cj] = __builtin_amdgcn_mfma_f32_16x16x32_bf16(                \
            (ar)[1], (bv)[1], acc[ci][cj], 0, 0, 0);                          \
    } while (0)

#define TILEW(u, SA13, S2, RDN, V2S, V4S)                                     \
    do {                                                                      \
        const int cur = (u) & 1, oth = cur ^ 1;                               \
        /* w1: quad (0,0) */                                                  \
        if (SA13) STG_A13((u) + 1);                                           \
        RD_B(cur, 1, b1);                                                     \
        __builtin_amdgcn_s_setprio(1);                                        \
        _Pragma("unroll") for (int m = 0; m < 4; ++m) {                       \
            MFMA4(aF[m], b0[0], m, 0);                                        \
            MFMA4(aF[m], b0[1], m, 1);                                        \
        }                                                                     \
        __builtin_amdgcn_s_setprio(0);                                        \
        asm volatile("s_waitcnt " V2S ::: "memory");                          \
        __builtin_amdgcn_s_barrier();                                         \
        /* w2: quad (0,1) + reload aF<-half1(cur) */                          \
        if (S2) STG_A02((u) + 2);                                             \
        __builtin_amdgcn_s_setprio(1);                                        \
        _Pragma("unroll") for (int m = 0; m < 4; ++m) {                       \
            MFMA4(aF[m], b1[0], m, 2);                                        \
            MFMA4(aF[m], b1[1], m, 3);                                        \
            RD_AF(cur, 1, m);                                                 \
        }                                                                     \
        __builtin_amdgcn_s_setprio(0);                                        \
        __builtin_amdgcn_s_barrier();                                         \
        /* w3: quad (1,1) */                                                  \
        if (S2) STG_B01((u) + 2);                                             \
        __builtin_amdgcn_s_setprio(1);                                        \
        _Pragma("unroll") for (int m = 0; m < 4; ++m) {                       \
            MFMA4(aF[m], b1[0], 4 + m, 2);                                    \
            MFMA4(aF[m], b1[1], 4 + m, 3);                                    \
        }                                                                     \
        __builtin_amdgcn_s_setprio(0);                                        \
        asm volatile("s_waitcnt " V4S ::: "memory");                          \
        __builtin_amdgcn_s_barrier();                                         \
        /* w4: quad (1,0) + reload aF<-half0(oth), b0<-oth */                 \
        if (S2) STG_B23((u) + 2);                                             \
        __builtin_amdgcn_s_setprio(1);                                        \
        _Pragma("unroll") for (int m = 0; m < 4; ++m) {                       \
            MFMA4(aF[m], b0[0], 4 + m, 0);                                    \
            MFMA4(aF[m], b0[1], 4 + m, 1);                                    \
            if (RDN) RD_AF(oth, 0, m);                                        \
        }                                                                     \
        __builtin_amdgcn_s_setprio(0);                                        \
        if (RDN) RD_B(oth, 0, b0);                                            \
        __builtin_amdgcn_s_barrier();                                         \
    } while (0)

template <bool OUT_BF16>
__global__ __launch_bounds__(512, 2) void gemm8(const u16* __restrict__ A, int lda,
                                                const u16* __restrict__ B,
                                                const float* __restrict__ bias,
                                                void* __restrict__ Cout,
                                                int K, int ldc) {
    __shared__ __align__(16) u16 As[2][16384];
    __shared__ __align__(16) u16 Bs[2][16384];

    const int tid = threadIdx.x;
    const int lane = tid & 63;
    const int wave = tid >> 6;
    const int wm = wave >> 2;  // 0..1  (row half, 128 rows)
    const int wn = wave & 3;   // 0..3  (col quarter, 64 cols)

    // T1: bijective XCD-aware block swizzle (m204 variant)
    const unsigned nwg = gridDim.x * gridDim.y;
    const unsigned orig = blockIdx.y * gridDim.x + blockIdx.x;
    const unsigned q = nwg >> 3, r = nwg & 7u;
    const unsigned xcd = orig & 7u, idx = orig >> 3;
    const unsigned wg =
        (xcd < r ? xcd * (q + 1) : r * (q + 1) + (xcd - r) * q) + idx;
    // column-major within the XCD chunk: consecutive wg share bn (B L2-reuse)
    const size_t bm = (size_t)(wg % gridDim.y) * 256;
    const size_t bn = (size_t)(wg / gridDim.y) * 256;

    f32x4 acc[8][4];
#pragma unroll
    for (int i = 0; i < 8; ++i)
#pragma unroll
        for (int j = 0; j < 4; ++j) acc[i][j] = (f32x4)0.f;

    // staging: thread covers row (tid>>3) of each 64-row block, 8 elems at
    // inverse-swizzled global col (rule #21: LDS dest linear).
    const int strow = tid >> 3;
    const int ssw = ((tid & 7) << 3) ^ ((strow & 7) << 3);
    const u16* aG = A + (bm + (size_t)strow) * (size_t)lda + ssw;
    const u16* bG = B + (bn + (size_t)strow) * (size_t)K + ssw;
    const size_t a64 = (size_t)64 * lda;
    const size_t b64 = (size_t)64 * K;

    // fragment read offsets (swizzled)
    const int lrow = lane & 15;
    const int hi8 = (lane >> 4) << 3;  // 0,8,16,24
    const int fswz = (lrow & 7) << 3;
    const int aK0 = hi8 ^ fswz;
    const int aK1 = (32 + hi8) ^ fswz;
    const int aRow = (wm * 128 + lrow) * 64;
    const int bRow = (wn * 64 + lrow) * 64;

    s16x8 aF[4][2], b0[2][2], b1[2][2];

    const int NT = K >> 6;  // K-tiles of 64 (>= 3 required)

    // prologue: tile0 full + tile1 {A02,B01,B23}. vmcnt(6) leaves tile1 trio.
    STG_A02(0);
    STG_A13(0);
    STG_B01(0);
    STG_B23(0);
    STG_A02(1);
    STG_B01(1);
    STG_B23(1);
    asm volatile("s_waitcnt vmcnt(6)" ::: "memory");
    __builtin_amdgcn_s_barrier();
#pragma unroll
    for (int m = 0; m < 4; ++m) RD_AF(0, 0, m);
    RD_B(0, 0, b0);

    for (int u = 0; u < NT - 2; ++u)
        TILEW(u, 1, 1, 1, "vmcnt(8)", "vmcnt(6)");
    TILEW(NT - 2, 1, 0, 1, "vmcnt(8)", "vmcnt(2)");
    TILEW(NT - 1, 0, 0, 0, "vmcnt(0)", "vmcnt(0)");

    // epilogue: C/D layout col=lane&15, row=(lane>>4)*4+reg
    const size_t crow0 = bm + wm * 128 + ((lane >> 4) << 2);
    const int ccol0 = (int)bn + wn * 64 + (lane & 15);
#pragma unroll
    for (int im = 0; im < 8; ++im) {
#pragma unroll
        for (int in = 0; in < 4; ++in) {
            const int col = ccol0 + in * 16;
            const float bv = bias[col];
            const size_t base = (crow0 + (size_t)im * 16) * (size_t)ldc + col;
#pragma unroll
            for (int r = 0; r < 4; ++r) {
                const float v = acc[im][in][r] + bv;
                if (OUT_BF16)
                    ((u16*)Cout)[base + (size_t)r * ldc] = f2bf(v);
                else
                    ((float*)Cout)[base + (size_t)r * ldc] = v;
            }
        }
    }
}

#undef STG_A02
#undef STG_A13
#undef STG_B01
#undef STG_B23
#undef RD_AF
#undef RD_B
#undef MFMA4
#undef TILEW

// ---------------- tiny attention S=2, IN-PLACE, coalesced -------------------
__device__ __forceinline__ void dot8(uint4 a, uint4 b, float& acc) {
    const unsigned* pa = (const unsigned*)&a;
    const unsigned* pb = (const unsigned*)&b;
#pragma unroll
    for (int i = 0; i < 4; ++i) {
        float alo, ahi, blo, bhi;
        unpack2(pa[i], alo, ahi);
        unpack2(pb[i], blo, bhi);
        acc += alo * blo + ahi * bhi;
    }
}

__global__ __launch_bounds__(256) void attn2(u16* __restrict__ qkv) {
    const int b = (blockIdx.x * 256 + threadIdx.x) >> 6;  // sample = global wave
    const int l = threadIdx.x & 63;
    u16* t0 = qkv + (size_t)(2 * b) * 6144;
    u16* t1 = t0 + 6144;
    const float scale = 0.0883883476483184f;  // 1/sqrt(128)
#pragma unroll
    for (int hg = 0; hg < 4; ++hg) {
        const int o = hg * 512 + l * 8;
        const uint4 q0 = *(const uint4*)(t0 + o);
        const uint4 q1 = *(const uint4*)(t1 + o);
        const uint4 k0 = *(const uint4*)(t0 + 2048 + o);
        const uint4 k1 = *(const uint4*)(t1 + 2048 + o);
        float s00 = 0.f, s01 = 0.f, s10 = 0.f, s11 = 0.f;
        dot8(q0, k0, s00);
        dot8(q0, k1, s01);
        dot8(q1, k0, s10);
        dot8(q1, k1, s11);
#pragma unroll
        for (int m = 1; m < 16; m <<= 1) {
            s00 += __shfl_xor(s00, m);
            s01 += __shfl_xor(s01, m);
            s10 += __shfl_xor(s10, m);
            s11 += __shfl_xor(s11, m);
        }
        s00 *= scale; s01 *= scale; s10 *= scale; s11 *= scale;
        const float m0 = fmaxf(s00, s01), m1 = fmaxf(s10, s11);
        const float e00 = __expf(s00 - m0), e01 = __expf(s01 - m0);
        const float e10 = __expf(s10 - m1), e11 = __expf(s11 - m1);
        const float r0 = 1.f / (e00 + e01), r1 = 1.f / (e10 + e11);
        const float p00 = e00 * r0, p01 = e01 * r0;
        const float p10 = e10 * r1, p11 = e11 * r1;
        const uint4 v0 = *(const uint4*)(t0 + 4096 + o);
        const uint4 v1 = *(const uint4*)(t1 + 4096 + o);
        const unsigned* pv0 = (const unsigned*)&v0;
        const unsigned* pv1 = (const unsigned*)&v1;
        uint4 c0v, c1v;
        unsigned* pc0 = (unsigned*)&c0v;
        unsigned* pc1 = (unsigned*)&c1v;
#pragma unroll
        for (int i = 0; i < 4; ++i) {
            float alo, ahi, blo, bhi;
            unpack2(pv0[i], alo, ahi);
            unpack2(pv1[i], blo, bhi);
            pc0[i] = pack2(p00 * alo + p01 * blo, p00 * ahi + p01 * bhi);
            pc1[i] = pack2(p10 * alo + p11 * blo, p10 * ahi + p11 * bhi);
        }
        *(uint4*)(t0 + o) = c0v;  // ctx token0 -> q-region
        *(uint4*)(t1 + o) = c1v;  // ctx token1 -> q-region
    }
}

// ---------------- LayerNorm C=2048 (bf16 in strided / out dense) ------------
__global__ __launch_bounds__(256) void ln_k(const u16* __restrict__ x, int ldx,
                                            const float* __restrict__ w,
                                            const float* __restrict__ bb,
                                            u16* __restrict__ y) {
    __shared__ float red[8];
    const int row = blockIdx.x;
    const int tid = threadIdx.x;
    const uint4 v = ((const uint4*)(x + (size_t)row * ldx))[tid];
    const unsigned* pw = (const unsigned*)&v;
    float f[8];
#pragma unroll
    for (int i = 0; i < 4; ++i) unpack2(pw[i], f[2 * i], f[2 * i + 1]);
    float s = 0.f, q = 0.f;
#pragma unroll
    for (int i = 0; i < 8; ++i) {
        s += f[i];
        q += f[i] * f[i];
    }
#pragma unroll
    for (int off = 32; off > 0; off >>= 1) {
        s += __shfl_down(s, off);
        q += __shfl_down(q, off);
    }
    if ((tid & 63) == 0) {
        red[tid >> 6] = s;
        red[4 + (tid >> 6)] = q;
    }
    __syncthreads();
    s = red[0] + red[1] + red[2] + red[3];
    q = red[4] + red[5] + red[6] + red[7];
    const float mu = s * (1.f / 2048.f);
    const float var = q * (1.f / 2048.f) - mu * mu;
    const float rstd = rsqrtf(var + 1e-5f);
    const float4 w0 = ((const float4*)w)[2 * tid];
    const float4 w1 = ((const float4*)w)[2 * tid + 1];
    const float4 b0 = ((const float4*)bb)[2 * tid];
    const float4 b1 = ((const float4*)bb)[2 * tid + 1];
    const float wv[8] = {w0.x, w0.y, w0.z, w0.w, w1.x, w1.y, w1.z, w1.w};
    const float bv[8] = {b0.x, b0.y, b0.z, b0.w, b1.x, b1.y, b1.z, b1.w};
    uint4 o;
    unsigned* po = (unsigned*)&o;
#pragma unroll
    for (int i = 0; i < 4; ++i) {
        float lo = (f[2 * i] - mu) * rstd * wv[2 * i] + bv[2 * i];
        float hi = (f[2 * i + 1] - mu) * rstd * wv[2 * i + 1] + bv[2 * i + 1];
        po[i] = pack2(lo, hi);
    }
    ((uint4*)(y + (size_t)row * 2048))[tid] = o;
}

// ------- fused = 0.5*(ln0+co0+ln1+co1); ln dense 2048, co stride 6144, ------
// ------- fused written at sample stride 12288 (q-region of token 2b) --------
__global__ __launch_bounds__(256) void mean_res(const u16* __restrict__ ln,
                                                const u16* __restrict__ co,
                                                u16* __restrict__ fused) {
    const int gid = blockIdx.x * 256 + threadIdx.x;  // CH*256
    const int b = gid >> 8;
    const int c8 = gid & 255;
    const uint4 l0 = ((const uint4*)(ln + (size_t)(2 * b) * 2048))[c8];
    const uint4 l1 = ((const uint4*)(ln + (size_t)(2 * b + 1) * 2048))[c8];
    const uint4 c0 = ((const uint4*)(co + (size_t)(2 * b) * 6144))[c8];
    const uint4 c1 = ((const uint4*)(co + (size_t)(2 * b + 1) * 6144))[c8];
    const unsigned* pl0 = (const unsigned*)&l0;
    const unsigned* pl1 = (const unsigned*)&l1;
    const unsigned* pc0 = (const unsigned*)&c0;
    const unsigned* pc1 = (const unsigned*)&c1;
    uint4 o;
    unsigned* po = (unsigned*)&o;
#pragma unroll
    for (int i = 0; i < 4; ++i) {
        float a_lo, a_hi, b_lo, b_hi, c_lo, c_hi, d_lo, d_hi;
        unpack2(pl0[i], a_lo, a_hi);
        unpack2(pl1[i], b_lo, b_hi);
        unpack2(pc0[i], c_lo, c_hi);
        unpack2(pc1[i], d_lo, d_hi);
        po[i] = pack2(0.5f * (a_lo + c_lo + b_lo + d_lo),
                      0.5f * (a_hi + c_hi + b_hi + d_hi));
    }
    ((uint4*)(fused + (size_t)b * 12288))[c8] = o;
}

extern "C" void kernel_launch(void* const* d_in, const int* in_sizes, int n_in,
                              void* d_out, int out_size, void* d_ws, size_t ws_size,
                              hipStream_t stream) {
    (void)in_sizes; (void)n_in; (void)out_size;
    const float* text   = (const float*)d_in[0];
    const float* graph  = (const float*)d_in[1];
    const float* Wt     = (const float*)d_in[2];
    const float* bt     = (const float*)d_in[3];
    const float* Wg     = (const float*)d_in[4];
    const float* bg     = (const float*)d_in[5];
    const float* Wqkv_s = (const float*)d_in[6];
    const float* bqkv_s = (const float*)d_in[7];
    const float* Wo_s   = (const float*)d_in[8];
    const float* bo_s   = (const float*)d_in[9];
    const float* Wqkv_c = (const float*)d_in[10];
    const float* bqkv_c = (const float*)d_in[11];
    const float* Wo_c   = (const float*)d_in[12];
    const float* bo_c   = (const float*)d_in[13];
    const float* ln_w   = (const float*)d_in[14];
    const float* ln_b   = (const float*)d_in[15];
    const float* Wout   = (const float*)d_in[16];
    const float* bout   = (const float*)d_in[17];
    float* out = (float*)d_out;

    // ---- weight area: 80 MiB of bf16 casts at base of ws (cast_w7 order) ----
    char* ws = (char*)d_ws;
    u16* wQs  = (u16*)ws;                          // 12,582,912 elems
    u16* wQc  = wQs + 12582912ull;
    u16* wOs  = wQc + 12582912ull;                 // 4,194,304
    u16* wOc  = wOs + 4194304ull;
    u16* wWt  = wOc + 4194304ull;                  // 4,194,304
    u16* wWg  = wWt + 4194304ull;                  // 2,097,152
    u16* wOut = wWg + 2097152ull;                  // 2,097,152
    const size_t WB = 83886080ull;                 // 80 MiB weight area

    // ---- chunk size: per-sample scratch = stacked 8KB + ln 8KB + qkv 24KB ----
    size_t CH = 8192;
    while (CH > 256 && WB + 40960ull * CH > ws_size) CH >>= 1;
    fprintf(stderr, "[kernel_launch] ws_size=%zu need=%zu CH=%zu\n",
            ws_size, WB + 40960ull * CH, CH);
    if (WB + 40960ull * CH > ws_size || d_ws == nullptr) return;

    const size_t T = 2 * CH;
    char* ca = ws + WB;                            // chunk area
    u16* stacked_c = (u16*)ca;                     // T*2048 elems, dense
    u16* ln_c      = (u16*)(ca + 4096 * T);        // T*2048 elems, dense
    u16* qkv_c     = (u16*)(ca + 8192 * T);        // T*6144 elems, stride 6144
    // input-cast staging reuses qkv_c (dead until S3 writes it)
    u16* tb_c = qkv_c;                             // CH*2048 bf16 text chunk
    u16* gb_c = qkv_c + (size_t)CH * 2048;         // CH*1024 bf16 graph chunk

    // ---- one-time fused weight cast (single launch) ----
    cast_w7<<<40960, 256, 0, stream>>>(Wqkv_s, Wqkv_c, Wo_s, Wo_c, Wt, Wg,
                                       Wout, wQs);

    const dim3 blk(256);
    const dim3 blk8(512);
    const unsigned gy  = (unsigned)(CH / 128);
    const unsigned gy8 = (unsigned)(CH / 256);     // 256-row tiles over CH rows
    const unsigned g8  = (unsigned)(T / 256);      // 256-row tiles over T tokens

    for (size_t c0 = 0; c0 < 8192; c0 += CH) {
        // S1: cast input chunks to bf16 (into dead qkv_c region), one launch
        {
            const int nt4 = (int)(CH * 512);
            const int ng4 = (int)(CH * 256);
            cast_in<<<(unsigned)((nt4 + ng4 + 255) / 256), blk, 0, stream>>>(
                text + c0 * 2048, graph + c0 * 1024, tb_c, gb_c, nt4, ng4);
        }
        // S2: projections -> interleaved stacked (token 2m=text, 2m+1=graph)
        gemm8<true><<<dim3(8, gy8), blk8, 0, stream>>>(
            tb_c, 2048, wWt, bt, stacked_c, 2048, 4096);
        gemm8<true><<<dim3(8, gy8), blk8, 0, stream>>>(
            gb_c, 1024, wWg, bg, stacked_c + 2048, 1024, 4096);
        // S3: self QKV -> qkv (ldc 6144), then in-place attention
        gemm8<true><<<dim3(24, g8), blk8, 0, stream>>>(
            stacked_c, 2048, wQs, bqkv_s, qkv_c, 2048, 6144);
        attn2<<<(unsigned)(CH / 4), blk, 0, stream>>>(qkv_c);
        // S4: self Wo: A=ctx (q-region, lda 6144) -> ao (v-region, ldc 6144)
        gemm8<true><<<dim3(8, g8), blk8, 0, stream>>>(
            qkv_c, 6144, wOs, bo_s, qkv_c + 4096, 2048, 6144);
        // S5: LayerNorm: ao (stride 6144) -> ln dense
        ln_k<<<(unsigned)T, blk, 0, stream>>>(qkv_c + 4096, 6144, ln_w, ln_b, ln_c);
        // S6: cross QKV: Q from ln -> q-region; K/V from stacked -> k,v regions
        gemm8<true><<<dim3(8, g8), blk8, 0, stream>>>(
            ln_c, 2048, wQc, bqkv_c, qkv_c, 2048, 6144);
        gemm8<true><<<dim3(16, g8), blk8, 0, stream>>>(
            stacked_c, 2048, wQc + 2048ull * 2048, bqkv_c + 2048,
            qkv_c + 2048, 2048, 6144);
        attn2<<<(unsigned)(CH / 4), blk, 0, stream>>>(qkv_c);
        // S7: cross Wo: A=ctx' (q-region) -> co (v-region)
        gemm8<true><<<dim3(8, g8), blk8, 0, stream>>>(
            qkv_c, 6144, wOc, bo_c, qkv_c + 4096, 2048, 6144);
        // S8: fused = mean_s(ln + co) -> q-region rows 2b (sample stride 12288)
        mean_res<<<(unsigned)CH, blk, 0, stream>>>(ln_c, qkv_c + 4096, qkv_c);
        // S9: final projection: A=fused (lda 12288) -> d_out fp32
        gemm_async<false><<<dim3(8, gy), blk, 0, stream>>>(
            qkv_c, 12288, wOut, bout, out + c0 * 1024, 2048, 1024);
    }
}

// Round 8
// 1701.457 us; speedup vs baseline: 1.1846x; 1.1846x over previous
//
#include <hip/hip_runtime.h>
#include <cstdio>

typedef unsigned short u16;
typedef float f32x4 __attribute__((ext_vector_type(4)));
typedef short s16x8 __attribute__((ext_vector_type(8)));

__device__ __forceinline__ u16 f2bf(float x) {
    unsigned u = __float_as_uint(x);
    u += 0x7fffu + ((u >> 16) & 1u);
    return (u16)(u >> 16);
}
__device__ __forceinline__ unsigned pack2(float a, float b) {
    return (unsigned)f2bf(a) | ((unsigned)f2bf(b) << 16);
}
__device__ __forceinline__ void unpack2(unsigned u, float& lo, float& hi) {
    lo = __uint_as_float(u << 16);
    hi = __uint_as_float(u & 0xffff0000u);
}

// async global->LDS, 16B per lane; LDS dest must be wave-uniform base + lane*16
__device__ __forceinline__ void gl2lds16(const u16* g, u16* l) {
    __builtin_amdgcn_global_load_lds(
        (const __attribute__((address_space(1))) void*)g,
        (__attribute__((address_space(3))) void*)l, 16, 0, 0);
}

// ---------------- fused one-time weight cast (7 tensors -> 80 MiB bf16) -----
__global__ __launch_bounds__(256) void cast_w7(
    const float* __restrict__ p0, const float* __restrict__ p1,
    const float* __restrict__ p2, const float* __restrict__ p3,
    const float* __restrict__ p4, const float* __restrict__ p5,
    const float* __restrict__ p6, u16* __restrict__ dst) {
    long i = (long)blockIdx.x * 256 + threadIdx.x;  // float4 index
    if (i >= 10485760L) return;
    const float* src;
    long base;
    if (i < 3145728L)      { src = p0; base = 0L; }
    else if (i < 6291456L) { src = p1; base = 3145728L; }
    else if (i < 7340032L) { src = p2; base = 6291456L; }
    else if (i < 8388608L) { src = p3; base = 7340032L; }
    else if (i < 9437184L) { src = p4; base = 8388608L; }
    else if (i < 9961472L) { src = p5; base = 9437184L; }
    else                   { src = p6; base = 9961472L; }
    float4 v = ((const float4*)src)[i - base];
    uint2 r;
    r.x = pack2(v.x, v.y);
    r.y = pack2(v.z, v.w);
    ((uint2*)dst)[i] = r;
}

// ---------------- fused per-chunk input cast (text + graph) -----------------
__global__ __launch_bounds__(256) void cast_in(const float* __restrict__ t,
                                               const float* __restrict__ g,
                                               u16* __restrict__ yt,
                                               u16* __restrict__ yg,
                                               int nt4, int ng4) {
    int i = blockIdx.x * 256 + threadIdx.x;
    const float* src;
    u16* dst;
    int idx;
    if (i < nt4) {
        src = t; dst = yt; idx = i;
    } else {
        idx = i - nt4;
        if (idx >= ng4) return;
        src = g; dst = yg;
    }
    float4 v = ((const float4*)src)[idx];
    uint2 r;
    r.x = pack2(v.x, v.y);
    r.y = pack2(v.z, v.w);
    ((uint2*)dst)[idx] = r;
}

// ---------------- async-staged GEMM (bf16 A w/ stride, bf16 B dense) --------
// m97 structure kept for small-N shapes (S9). 128x128 tile, BK=32.
template <bool OUT_BF16>
__global__ __launch_bounds__(256) void gemm_async(const u16* __restrict__ A, int lda,
                                                  const u16* __restrict__ B,
                                                  const float* __restrict__ bias,
                                                  void* __restrict__ Cout,
                                                  int K, int ldc) {
    __shared__ __align__(16) u16 As[128 * 32];
    __shared__ __align__(16) u16 Bs[128 * 32];

    const int tid = threadIdx.x;
    const int lane = tid & 63;
    const int wave = tid >> 6;
    const int wm = wave >> 1;
    const int wn = wave & 1;
    const size_t bm = (size_t)blockIdx.y * 128;
    const size_t bn = (size_t)blockIdx.x * 128;

    f32x4 acc[4][4];
#pragma unroll
    for (int i = 0; i < 4; ++i)
#pragma unroll
        for (int j = 0; j < 4; ++j) acc[i][j] = (f32x4)0.f;

    const int srow = tid >> 2;        // 0..63
    const int scol = (tid & 3) << 3;  // 0,8,16,24
    const u16* Ag = A + (bm + (size_t)srow) * (size_t)lda + scol;
    const u16* Bg = B + (bn + (size_t)srow) * (size_t)K + scol;
    const size_t rA = (size_t)64 * lda;
    const size_t rB = (size_t)64 * K;
    u16* lA0 = &As[tid * 8];
    u16* lA1 = &As[2048 + tid * 8];
    u16* lB0 = &Bs[tid * 8];
    u16* lB1 = &Bs[2048 + tid * 8];

    const int lrow = lane & 15;
    const int lk = (lane >> 4) << 3;

    const int niter = K >> 5;
    for (int t = 0; t < niter; ++t) {
        __syncthreads();
        gl2lds16(Ag, lA0);
        gl2lds16(Ag + rA, lA1);
        gl2lds16(Bg, lB0);
        gl2lds16(Bg + rB, lB1);
        Ag += 32;
        Bg += 32;
        __syncthreads();
        s16x8 af[4], bfr[4];
#pragma unroll
        for (int i = 0; i < 4; ++i)
            af[i] = *(const s16x8*)&As[(wm * 64 + i * 16 + lrow) * 32 + lk];
#pragma unroll
        for (int j = 0; j < 4; ++j)
            bfr[j] = *(const s16x8*)&Bs[(wn * 64 + j * 16 + lrow) * 32 + lk];
#pragma unroll
        for (int i = 0; i < 4; ++i)
#pragma unroll
            for (int j = 0; j < 4; ++j)
                acc[i][j] = __builtin_amdgcn_mfma_f32_16x16x32_bf16(
                    af[i], bfr[j], acc[i][j], 0, 0, 0);
    }

    const size_t crow0 = bm + wm * 64 + ((lane >> 4) << 2);
    const int ccol0 = (int)bn + wn * 64 + (lane & 15);
#pragma unroll
    for (int i = 0; i < 4; ++i) {
#pragma unroll
        for (int j = 0; j < 4; ++j) {
            const int col = ccol0 + j * 16;
            const float bv = bias[col];
            const size_t base = (crow0 + (size_t)i * 16) * (size_t)ldc + col;
#pragma unroll
            for (int r = 0; r < 4; ++r) {
                const float v = acc[i][j][r] + bv;
                if (OUT_BF16)
                    ((u16*)Cout)[base + (size_t)r * ldc] = f2bf(v);
                else
                    ((float*)Cout)[base + (size_t)r * ldc] = v;
            }
        }
    }
}

// ---------------- 256x256 4-window GEMM with read/MFMA overlap --------------
// R5 schedule + R5 row-major mapping (both proven best: 210 µs; R6 single-buf
// and R7 col-major both regressed). Body factored out so gemm8d can merge two
// independent GEMM parts into one launch (launch-gap + tail-balance win).
#define STG_A02(v)                                                            \
    do {                                                                      \
        gl2lds16(aG + (size_t)(v) * 64, &As[(v) & 1][tid * 8]);               \
        gl2lds16(aG + 2 * a64 + (size_t)(v) * 64,                             \
                 &As[(v) & 1][8192 + tid * 8]);                               \
    } while (0)
#define STG_A13(v)                                                            \
    do {                                                                      \
        gl2lds16(aG + a64 + (size_t)(v) * 64, &As[(v) & 1][4096 + tid * 8]);  \
        gl2lds16(aG + 3 * a64 + (size_t)(v) * 64,                             \
                 &As[(v) & 1][12288 + tid * 8]);                              \
    } while (0)
#define STG_B01(v)                                                            \
    do {                                                                      \
        gl2lds16(bG + (size_t)(v) * 64, &Bs[(v) & 1][tid * 8]);               \
        gl2lds16(bG + b64 + (size_t)(v) * 64, &Bs[(v) & 1][4096 + tid * 8]);  \
    } while (0)
#define STG_B23(v)                                                            \
    do {                                                                      \
        gl2lds16(bG + 2 * b64 + (size_t)(v) * 64,                             \
                 &Bs[(v) & 1][8192 + tid * 8]);                               \
        gl2lds16(bG + 3 * b64 + (size_t)(v) * 64,                             \
                 &Bs[(v) & 1][12288 + tid * 8]);                              \
    } while (0)
#define RD_AF(buf, mh, m)                                                     \
    do {                                                                      \
        const u16* p_ = &As[buf][aRow + ((mh) * 64 + (m) * 16) * 64];         \
        aF[m][0] = *(const s16x8*)(p_ + aK0);                                 \
        aF[m][1] = *(const s16x8*)(p_ + aK1);                                 \
    } while (0)
#define RD_B(buf, nh, dst)                                                    \
    do {                                                                      \
        _Pragma("unroll") for (int n_ = 0; n_ < 2; ++n_) {                    \
            const u16* p_ = &Bs[buf][bRow + ((nh) * 32 + n_ * 16) * 64];      \
            dst[n_][0] = *(const s16x8*)(p_ + aK0);                           \
            dst[n_][1] = *(const s16x8*)(p_ + aK1);                           \
        }                                                                     \
    } while (0)
#define MFMA4(ar, bv, ci, cj)                                                 \
    do {                                                                      \
        acc[ci][cj] = __builtin_amdgcn_mfma_f32_16x16x32_bf16(                \
            (ar)[0], (bv)[0], acc[ci][cj], 0, 0, 0);                          \
        acc[ci][cj] = __builtin_amdgcn_mfma_f32_16x16x32_bf16(                \
            (ar)[1], (bv)[1], acc[ci][cj], 0, 0, 0);                          \
    } while (0)

#define TILEW(u, SA13, S2, RDN, V2S, V4S)                                     \
    do {                                                                      \
        const int cur = (u) & 1, oth = cur ^ 1;                               \
        /* w1: quad (0,0) */                                                  \
        if (SA13) STG_A13((u) + 1);                                           \
        RD_B(cur, 1, b1);                                                     \
        __builtin_amdgcn_s_setprio(1);                                        \
        _Pragma("unroll") for (int m = 0; m < 4; ++m) {                       \
            MFMA4(aF[m], b0[0], m, 0);                                        \
            MFMA4(aF[m], b0[1], m, 1);                                        \
        }                                                                     \
        __builtin_amdgcn_s_setprio(0);                                        \
        asm volatile("s_waitcnt " V2S ::: "memory");                          \
        __builtin_amdgcn_s_barrier();                                         \
        /* w2: quad (0,1) + reload aF<-half1(cur) */                          \
        if (S2) STG_A02((u) + 2);                                             \
        __builtin_amdgcn_s_setprio(1);                                        \
        _Pragma("unroll") for (int m = 0; m < 4; ++m) {                       \
            MFMA4(aF[m], b1[0], m, 2);                                        \
            MFMA4(aF[m], b1[1], m, 3);                                        \
            RD_AF(cur, 1, m);                                                 \
        }                                                                     \
        __builtin_amdgcn_s_setprio(0);                                        \
        __builtin_amdgcn_s_barrier();                                         \
        /* w3: quad (1,1) */                                                  \
        if (S2) STG_B01((u) + 2);                                             \
        __builtin_amdgcn_s_setprio(1);                                        \
        _Pragma("unroll") for (int m = 0; m < 4; ++m) {                       \
            MFMA4(aF[m], b1[0], 4 + m, 2);                                    \
            MFMA4(aF[m], b1[1], 4 + m, 3);                                    \
        }                                                                     \
        __builtin_amdgcn_s_setprio(0);                                        \
        asm volatile("s_waitcnt " V4S ::: "memory");                          \
        __builtin_amdgcn_s_barrier();                                         \
        /* w4: quad (1,0) + reload aF<-half0(oth), b0<-oth */                 \
        if (S2) STG_B23((u) + 2);                                             \
        __builtin_amdgcn_s_setprio(1);                                        \
        _Pragma("unroll") for (int m = 0; m < 4; ++m) {                       \
            MFMA4(aF[m], b0[0], 4 + m, 0);                                    \
            MFMA4(aF[m], b0[1], 4 + m, 1);                                    \
            if (RDN) RD_AF(oth, 0, m);                                        \
        }                                                                     \
        __builtin_amdgcn_s_setprio(0);                                        \
        if (RDN) RD_B(oth, 0, b0);                                            \
        __builtin_amdgcn_s_barrier();                                         \
    } while (0)

template <bool OUT_BF16>
__device__ __forceinline__ void gemm8_body(
    const u16* __restrict__ A, int lda, const u16* __restrict__ B,
    const float* __restrict__ bias, void* __restrict__ Cout, int K, int ldc,
    size_t bm, size_t bn, u16 (*As)[16384], u16 (*Bs)[16384]) {
    const int tid = threadIdx.x;
    const int lane = tid & 63;
    const int wave = tid >> 6;
    const int wm = wave >> 2;  // 0..1  (row half, 128 rows)
    const int wn = wave & 3;   // 0..3  (col quarter, 64 cols)

    f32x4 acc[8][4];
#pragma unroll
    for (int i = 0; i < 8; ++i)
#pragma unroll
        for (int j = 0; j < 4; ++j) acc[i][j] = (f32x4)0.f;

    // staging: thread covers row (tid>>3) of each 64-row block, 8 elems at
    // inverse-swizzled global col (rule #21: LDS dest linear).
    const int strow = tid >> 3;
    const int ssw = ((tid & 7) << 3) ^ ((strow & 7) << 3);
    const u16* aG = A + (bm + (size_t)strow) * (size_t)lda + ssw;
    const u16* bG = B + (bn + (size_t)strow) * (size_t)K + ssw;
    const size_t a64 = (size_t)64 * lda;
    const size_t b64 = (size_t)64 * K;

    // fragment read offsets (swizzled)
    const int lrow = lane & 15;
    const int hi8 = (lane >> 4) << 3;  // 0,8,16,24
    const int fswz = (lrow & 7) << 3;
    const int aK0 = hi8 ^ fswz;
    const int aK1 = (32 + hi8) ^ fswz;
    const int aRow = (wm * 128 + lrow) * 64;
    const int bRow = (wn * 64 + lrow) * 64;

    s16x8 aF[4][2], b0[2][2], b1[2][2];

    const int NT = K >> 6;  // K-tiles of 64 (>= 3 required)

    // prologue: tile0 full + tile1 {A02,B01,B23}. vmcnt(6) leaves tile1 trio.
    STG_A02(0);
    STG_A13(0);
    STG_B01(0);
    STG_B23(0);
    STG_A02(1);
    STG_B01(1);
    STG_B23(1);
    asm volatile("s_waitcnt vmcnt(6)" ::: "memory");
    __builtin_amdgcn_s_barrier();
#pragma unroll
    for (int m = 0; m < 4; ++m) RD_AF(0, 0, m);
    RD_B(0, 0, b0);

    for (int u = 0; u < NT - 2; ++u)
        TILEW(u, 1, 1, 1, "vmcnt(8)", "vmcnt(6)");
    TILEW(NT - 2, 1, 0, 1, "vmcnt(8)", "vmcnt(2)");
    TILEW(NT - 1, 0, 0, 0, "vmcnt(0)", "vmcnt(0)");

    // epilogue: C/D layout col=lane&15, row=(lane>>4)*4+reg
    const size_t crow0 = bm + wm * 128 + ((lane >> 4) << 2);
    const int ccol0 = (int)bn + wn * 64 + (lane & 15);
#pragma unroll
    for (int im = 0; im < 8; ++im) {
#pragma unroll
        for (int in = 0; in < 4; ++in) {
            const int col = ccol0 + in * 16;
            const float bv = bias[col];
            const size_t base = (crow0 + (size_t)im * 16) * (size_t)ldc + col;
#pragma unroll
            for (int r = 0; r < 4; ++r) {
                const float v = acc[im][in][r] + bv;
                if (OUT_BF16)
                    ((u16*)Cout)[base + (size_t)r * ldc] = f2bf(v);
                else
                    ((float*)Cout)[base + (size_t)r * ldc] = v;
            }
        }
    }
}

// bijective XCD swizzle + R5 row-major tile mapping
__device__ __forceinline__ void swz_map(unsigned& bmi, unsigned& bni) {
    const unsigned nwg = gridDim.x * gridDim.y;
    const unsigned orig = blockIdx.y * gridDim.x + blockIdx.x;
    const unsigned q = nwg >> 3, r = nwg & 7u;
    const unsigned xcd = orig & 7u, idx = orig >> 3;
    const unsigned wg =
        (xcd < r ? xcd * (q + 1) : r * (q + 1) + (xcd - r) * q) + idx;
    bmi = wg / gridDim.x;
    bni = wg % gridDim.x;
}

template <bool OUT_BF16>
__global__ __launch_bounds__(512, 2) void gemm8(const u16* __restrict__ A, int lda,
                                                const u16* __restrict__ B,
                                                const float* __restrict__ bias,
                                                void* __restrict__ Cout,
                                                int K, int ldc) {
    __shared__ __align__(16) u16 As[2][16384];
    __shared__ __align__(16) u16 Bs[2][16384];
    unsigned bmi, bni;
    swz_map(bmi, bni);
    gemm8_body<OUT_BF16>(A, lda, B, bias, Cout, K, ldc, (size_t)bmi * 256,
                         (size_t)bni * 256, As, Bs);
}

// two independent GEMM parts in one launch; part chosen by swizzled bn tile.
// Both parts share M (grid y) and ldc.
template <bool OUT_BF16>
__global__ __launch_bounds__(512, 2) void gemm8d(
    const u16* __restrict__ A0, int lda0, const u16* __restrict__ B0,
    const float* __restrict__ bias0, void* __restrict__ C0, int K0, int nx0,
    const u16* __restrict__ A1, int lda1, const u16* __restrict__ B1,
    const float* __restrict__ bias1, void* __restrict__ C1, int K1, int ldc) {
    __shared__ __align__(16) u16 As[2][16384];
    __shared__ __align__(16) u16 Bs[2][16384];
    unsigned bmi, bni;
    swz_map(bmi, bni);
    if ((int)bni < nx0)
        gemm8_body<OUT_BF16>(A0, lda0, B0, bias0, C0, K0, ldc,
                             (size_t)bmi * 256, (size_t)bni * 256, As, Bs);
    else
        gemm8_body<OUT_BF16>(A1, lda1, B1, bias1, C1, K1, ldc,
                             (size_t)bmi * 256, (size_t)(bni - nx0) * 256, As,
                             Bs);
}

#undef STG_A02
#undef STG_A13
#undef STG_B01
#undef STG_B23
#undef RD_AF
#undef RD_B
#undef MFMA4
#undef TILEW

// ---------------- tiny attention S=2, IN-PLACE, coalesced -------------------
__device__ __forceinline__ void dot8(uint4 a, uint4 b, float& acc) {
    const unsigned* pa = (const unsigned*)&a;
    const unsigned* pb = (const unsigned*)&b;
#pragma unroll
    for (int i = 0; i < 4; ++i) {
        float alo, ahi, blo, bhi;
        unpack2(pa[i], alo, ahi);
        unpack2(pb[i], blo, bhi);
        acc += alo * blo + ahi * bhi;
    }
}

__global__ __launch_bounds__(256) void attn2(u16* __restrict__ qkv) {
    const int b = (blockIdx.x * 256 + threadIdx.x) >> 6;  // sample = global wave
    const int l = threadIdx.x & 63;
    u16* t0 = qkv + (size_t)(2 * b) * 6144;
    u16* t1 = t0 + 6144;
    const float scale = 0.0883883476483184f;  // 1/sqrt(128)
#pragma unroll
    for (int hg = 0; hg < 4; ++hg) {
        const int o = hg * 512 + l * 8;
        const uint4 q0 = *(const uint4*)(t0 + o);
        const uint4 q1 = *(const uint4*)(t1 + o);
        const uint4 k0 = *(const uint4*)(t0 + 2048 + o);
        const uint4 k1 = *(const uint4*)(t1 + 2048 + o);
        float s00 = 0.f, s01 = 0.f, s10 = 0.f, s11 = 0.f;
        dot8(q0, k0, s00);
        dot8(q0, k1, s01);
        dot8(q1, k0, s10);
        dot8(q1, k1, s11);
#pragma unroll
        for (int m = 1; m < 16; m <<= 1) {
            s00 += __shfl_xor(s00, m);
            s01 += __shfl_xor(s01, m);
            s10 += __shfl_xor(s10, m);
            s11 += __shfl_xor(s11, m);
        }
        s00 *= scale; s01 *= scale; s10 *= scale; s11 *= scale;
        const float m0 = fmaxf(s00, s01), m1 = fmaxf(s10, s11);
        const float e00 = __expf(s00 - m0), e01 = __expf(s01 - m0);
        const float e10 = __expf(s10 - m1), e11 = __expf(s11 - m1);
        const float r0 = 1.f / (e00 + e01), r1 = 1.f / (e10 + e11);
        const float p00 = e00 * r0, p01 = e01 * r0;
        const float p10 = e10 * r1, p11 = e11 * r1;
        const uint4 v0 = *(const uint4*)(t0 + 4096 + o);
        const uint4 v1 = *(const uint4*)(t1 + 4096 + o);
        const unsigned* pv0 = (const unsigned*)&v0;
        const unsigned* pv1 = (const unsigned*)&v1;
        uint4 c0v, c1v;
        unsigned* pc0 = (unsigned*)&c0v;
        unsigned* pc1 = (unsigned*)&c1v;
#pragma unroll
        for (int i = 0; i < 4; ++i) {
            float alo, ahi, blo, bhi;
            unpack2(pv0[i], alo, ahi);
            unpack2(pv1[i], blo, bhi);
            pc0[i] = pack2(p00 * alo + p01 * blo, p00 * ahi + p01 * bhi);
            pc1[i] = pack2(p10 * alo + p11 * blo, p10 * ahi + p11 * bhi);
        }
        *(uint4*)(t0 + o) = c0v;  // ctx token0 -> q-region
        *(uint4*)(t1 + o) = c1v;  // ctx token1 -> q-region
    }
}

// ---------------- LayerNorm C=2048 (bf16 in strided / out dense) ------------
__global__ __launch_bounds__(256) void ln_k(const u16* __restrict__ x, int ldx,
                                            const float* __restrict__ w,
                                            const float* __restrict__ bb,
                                            u16* __restrict__ y) {
    __shared__ float red[8];
    const int row = blockIdx.x;
    const int tid = threadIdx.x;
    const uint4 v = ((const uint4*)(x + (size_t)row * ldx))[tid];
    const unsigned* pw = (const unsigned*)&v;
    float f[8];
#pragma unroll
    for (int i = 0; i < 4; ++i) unpack2(pw[i], f[2 * i], f[2 * i + 1]);
    float s = 0.f, q = 0.f;
#pragma unroll
    for (int i = 0; i < 8; ++i) {
        s += f[i];
        q += f[i] * f[i];
    }
#pragma unroll
    for (int off = 32; off > 0; off >>= 1) {
        s += __shfl_down(s, off);
        q += __shfl_down(q, off);
    }
    if ((tid & 63) == 0) {
        red[tid >> 6] = s;
        red[4 + (tid >> 6)] = q;
    }
    __syncthreads();
    s = red[0] + red[1] + red[2] + red[3];
    q = red[4] + red[5] + red[6] + red[7];
    const float mu = s * (1.f / 2048.f);
    const float var = q * (1.f / 2048.f) - mu * mu;
    const float rstd = rsqrtf(var + 1e-5f);
    const float4 w0 = ((const float4*)w)[2 * tid];
    const float4 w1 = ((const float4*)w)[2 * tid + 1];
    const float4 b0 = ((const float4*)bb)[2 * tid];
    const float4 b1 = ((const float4*)bb)[2 * tid + 1];
    const float wv[8] = {w0.x, w0.y, w0.z, w0.w, w1.x, w1.y, w1.z, w1.w};
    const float bv[8] = {b0.x, b0.y, b0.z, b0.w, b1.x, b1.y, b1.z, b1.w};
    uint4 o;
    unsigned* po = (unsigned*)&o;
#pragma unroll
    for (int i = 0; i < 4; ++i) {
        float lo = (f[2 * i] - mu) * rstd * wv[2 * i] + bv[2 * i];
        float hi = (f[2 * i + 1] - mu) * rstd * wv[2 * i + 1] + bv[2 * i + 1];
        po[i] = pack2(lo, hi);
    }
    ((uint4*)(y + (size_t)row * 2048))[tid] = o;
}

// ------- fused = 0.5*(ln0+co0+ln1+co1); ln dense 2048, co stride 6144, ------
// ------- fused written at sample stride 12288 (q-region of token 2b) --------
__global__ __launch_bounds__(256) void mean_res(const u16* __restrict__ ln,
                                                const u16* __restrict__ co,
                                                u16* __restrict__ fused) {
    const int gid = blockIdx.x * 256 + threadIdx.x;  // CH*256
    const int b = gid >> 8;
    const int c8 = gid & 255;
    const uint4 l0 = ((const uint4*)(ln + (size_t)(2 * b) * 2048))[c8];
    const uint4 l1 = ((const uint4*)(ln + (size_t)(2 * b + 1) * 2048))[c8];
    const uint4 c0 = ((const uint4*)(co + (size_t)(2 * b) * 6144))[c8];
    const uint4 c1 = ((const uint4*)(co + (size_t)(2 * b + 1) * 6144))[c8];
    const unsigned* pl0 = (const unsigned*)&l0;
    const unsigned* pl1 = (const unsigned*)&l1;
    const unsigned* pc0 = (const unsigned*)&c0;
    const unsigned* pc1 = (const unsigned*)&c1;
    uint4 o;
    unsigned* po = (unsigned*)&o;
#pragma unroll
    for (int i = 0; i < 4; ++i) {
        float a_lo, a_hi, b_lo, b_hi, c_lo, c_hi, d_lo, d_hi;
        unpack2(pl0[i], a_lo, a_hi);
        unpack2(pl1[i], b_lo, b_hi);
        unpack2(pc0[i], c_lo, c_hi);
        unpack2(pc1[i], d_lo, d_hi);
        po[i] = pack2(0.5f * (a_lo + c_lo + b_lo + d_lo),
                      0.5f * (a_hi + c_hi + b_hi + d_hi));
    }
    ((uint4*)(fused + (size_t)b * 12288))[c8] = o;
}

extern "C" void kernel_launch(void* const* d_in, const int* in_sizes, int n_in,
                              void* d_out, int out_size, void* d_ws, size_t ws_size,
                              hipStream_t stream) {
    (void)in_sizes; (void)n_in; (void)out_size;
    const float* text   = (const float*)d_in[0];
    const float* graph  = (const float*)d_in[1];
    const float* Wt     = (const float*)d_in[2];
    const float* bt     = (const float*)d_in[3];
    const float* Wg     = (const float*)d_in[4];
    const float* bg     = (const float*)d_in[5];
    const float* Wqkv_s = (const float*)d_in[6];
    const float* bqkv_s = (const float*)d_in[7];
    const float* Wo_s   = (const float*)d_in[8];
    const float* bo_s   = (const float*)d_in[9];
    const float* Wqkv_c = (const float*)d_in[10];
    const float* bqkv_c = (const float*)d_in[11];
    const float* Wo_c   = (const float*)d_in[12];
    const float* bo_c   = (const float*)d_in[13];
    const float* ln_w   = (const float*)d_in[14];
    const float* ln_b   = (const float*)d_in[15];
    const float* Wout   = (const float*)d_in[16];
    const float* bout   = (const float*)d_in[17];
    float* out = (float*)d_out;

    // ---- weight area: 80 MiB of bf16 casts at base of ws (cast_w7 order) ----
    char* ws = (char*)d_ws;
    u16* wQs  = (u16*)ws;                          // 12,582,912 elems
    u16* wQc  = wQs + 12582912ull;
    u16* wOs  = wQc + 12582912ull;                 // 4,194,304
    u16* wOc  = wOs + 4194304ull;
    u16* wWt  = wOc + 4194304ull;                  // 4,194,304
    u16* wWg  = wWt + 4194304ull;                  // 2,097,152
    u16* wOut = wWg + 2097152ull;                  // 2,097,152
    const size_t WB = 83886080ull;                 // 80 MiB weight area

    // ---- chunk size: per-sample scratch = stacked 8KB + ln 8KB + qkv 24KB ----
    size_t CH = 8192;
    while (CH > 256 && WB + 40960ull * CH > ws_size) CH >>= 1;
    fprintf(stderr, "[kernel_launch] ws_size=%zu need=%zu CH=%zu\n",
            ws_size, WB + 40960ull * CH, CH);
    if (WB + 40960ull * CH > ws_size || d_ws == nullptr) return;

    const size_t T = 2 * CH;
    char* ca = ws + WB;                            // chunk area
    u16* stacked_c = (u16*)ca;                     // T*2048 elems, dense
    u16* ln_c      = (u16*)(ca + 4096 * T);        // T*2048 elems, dense
    u16* qkv_c     = (u16*)(ca + 8192 * T);        // T*6144 elems, stride 6144
    // input-cast staging reuses qkv_c (dead until S3 writes it)
    u16* tb_c = qkv_c;                             // CH*2048 bf16 text chunk
    u16* gb_c = qkv_c + (size_t)CH * 2048;         // CH*1024 bf16 graph chunk

    // ---- one-time fused weight cast (single launch) ----
    cast_w7<<<40960, 256, 0, stream>>>(Wqkv_s, Wqkv_c, Wo_s, Wo_c, Wt, Wg,
                                       Wout, wQs);

    const dim3 blk(256);
    const dim3 blk8(512);
    const unsigned gy  = (unsigned)(CH / 128);
    const unsigned gy8 = (unsigned)(CH / 256);     // 256-row tiles over CH rows
    const unsigned g8  = (unsigned)(T / 256);      // 256-row tiles over T tokens

    for (size_t c0 = 0; c0 < 8192; c0 += CH) {
        // S1: cast input chunks to bf16 (into dead qkv_c region), one launch
        {
            const int nt4 = (int)(CH * 512);
            const int ng4 = (int)(CH * 256);
            cast_in<<<(unsigned)((nt4 + ng4 + 255) / 256), blk, 0, stream>>>(
                text + c0 * 2048, graph + c0 * 1024, tb_c, gb_c, nt4, ng4);
        }
        // S2: both projections in ONE launch (text: 8 bn-tiles K=2048;
        //     graph: 8 bn-tiles K=1024) -> interleaved stacked
        gemm8d<true><<<dim3(16, gy8), blk8, 0, stream>>>(
            tb_c, 2048, wWt, bt, stacked_c, 2048, 8,
            gb_c, 1024, wWg, bg, stacked_c + 2048, 1024, 4096);
        // S3: self QKV -> qkv (ldc 6144), then in-place attention
        gemm8<true><<<dim3(24, g8), blk8, 0, stream>>>(
            stacked_c, 2048, wQs, bqkv_s, qkv_c, 2048, 6144);
        attn2<<<(unsigned)(CH / 4), blk, 0, stream>>>(qkv_c);
        // S4: self Wo: A=ctx (q-region, lda 6144) -> ao (v-region, ldc 6144)
        gemm8<true><<<dim3(8, g8), blk8, 0, stream>>>(
            qkv_c, 6144, wOs, bo_s, qkv_c + 4096, 2048, 6144);
        // S5: LayerNorm: ao (stride 6144) -> ln dense
        ln_k<<<(unsigned)T, blk, 0, stream>>>(qkv_c + 4096, 6144, ln_w, ln_b, ln_c);
        // S6: cross QKV in ONE launch (Q from ln: 8 tiles; K/V from stacked:
        //     16 tiles) -> q / k,v regions
        gemm8d<true><<<dim3(24, g8), blk8, 0, stream>>>(
            ln_c, 2048, wQc, bqkv_c, qkv_c, 2048, 8,
            stacked_c, 2048, wQc + 2048ull * 2048, bqkv_c + 2048,
            qkv_c + 2048, 2048, 6144);
        attn2<<<(unsigned)(CH / 4), blk, 0, stream>>>(qkv_c);
        // S7: cross Wo: A=ctx' (q-region) -> co (v-region)
        gemm8<true><<<dim3(8, g8), blk8, 0, stream>>>(
            qkv_c, 6144, wOc, bo_c, qkv_c + 4096, 2048, 6144);
        // S8: fused = mean_s(ln + co) -> q-region rows 2b (sample stride 12288)
        mean_res<<<(unsigned)CH, blk, 0, stream>>>(ln_c, qkv_c + 4096, qkv_c);
        // S9: final projection: A=fused (lda 12288) -> d_out fp32
        gemm_async<false><<<dim3(8, gy), blk, 0, stream>>>(
            qkv_c, 12288, wOut, bout, out + c0 * 1024, 2048, 1024);
    }
}

// Round 9
// 1686.799 us; speedup vs baseline: 1.1949x; 1.0087x over previous
//
#include <hip/hip_runtime.h>
#include <cstdio>

typedef unsigned short u16;
typedef float f32x4 __attribute__((ext_vector_type(4)));
typedef short s16x8 __attribute__((ext_vector_type(8)));

__device__ __forceinline__ u16 f2bf(float x) {
    unsigned u = __float_as_uint(x);
    u += 0x7fffu + ((u >> 16) & 1u);
    return (u16)(u >> 16);
}
__device__ __forceinline__ float bf2f(u16 x) {
    return __uint_as_float((unsigned)x << 16);
}
__device__ __forceinline__ unsigned pack2(float a, float b) {
    return (unsigned)f2bf(a) | ((unsigned)f2bf(b) << 16);
}
__device__ __forceinline__ void unpack2(unsigned u, float& lo, float& hi) {
    lo = __uint_as_float(u << 16);
    hi = __uint_as_float(u & 0xffff0000u);
}

// async global->LDS, 16B per lane; LDS dest must be wave-uniform base + lane*16
__device__ __forceinline__ void gl2lds16(const u16* g, u16* l) {
    __builtin_amdgcn_global_load_lds(
        (const __attribute__((address_space(1))) void*)g,
        (__attribute__((address_space(3))) void*)l, 16, 0, 0);
}

// ---------------- fused one-time weight cast (7 tensors -> 80 MiB bf16) -----
__global__ __launch_bounds__(256) void cast_w7(
    const float* __restrict__ p0, const float* __restrict__ p1,
    const float* __restrict__ p2, const float* __restrict__ p3,
    const float* __restrict__ p4, const float* __restrict__ p5,
    const float* __restrict__ p6, u16* __restrict__ dst) {
    long i = (long)blockIdx.x * 256 + threadIdx.x;  // float4 index
    if (i >= 10485760L) return;
    const float* src;
    long base;
    if (i < 3145728L)      { src = p0; base = 0L; }
    else if (i < 6291456L) { src = p1; base = 3145728L; }
    else if (i < 7340032L) { src = p2; base = 6291456L; }
    else if (i < 8388608L) { src = p3; base = 7340032L; }
    else if (i < 9437184L) { src = p4; base = 8388608L; }
    else if (i < 9961472L) { src = p5; base = 9437184L; }
    else                   { src = p6; base = 9961472L; }
    float4 v = ((const float4*)src)[i - base];
    uint2 r;
    r.x = pack2(v.x, v.y);
    r.y = pack2(v.z, v.w);
    ((uint2*)dst)[i] = r;
}

// ---------------- fused per-chunk input cast (text + graph) -----------------
__global__ __launch_bounds__(256) void cast_in(const float* __restrict__ t,
                                               const float* __restrict__ g,
                                               u16* __restrict__ yt,
                                               u16* __restrict__ yg,
                                               int nt4, int ng4) {
    int i = blockIdx.x * 256 + threadIdx.x;
    const float* src;
    u16* dst;
    int idx;
    if (i < nt4) {
        src = t; dst = yt; idx = i;
    } else {
        idx = i - nt4;
        if (idx >= ng4) return;
        src = g; dst = yg;
    }
    float4 v = ((const float4*)src)[idx];
    uint2 r;
    r.x = pack2(v.x, v.y);
    r.y = pack2(v.z, v.w);
    ((uint2*)dst)[idx] = r;
}

// ---------------- async-staged GEMM (bf16 A w/ stride, bf16 B dense) --------
// m97 structure kept for small-N shapes (S9). 128x128 tile, BK=32.
template <bool OUT_BF16>
__global__ __launch_bounds__(256) void gemm_async(const u16* __restrict__ A, int lda,
                                                  const u16* __restrict__ B,
                                                  const float* __restrict__ bias,
                                                  void* __restrict__ Cout,
                                                  int K, int ldc) {
    __shared__ __align__(16) u16 As[128 * 32];
    __shared__ __align__(16) u16 Bs[128 * 32];

    const int tid = threadIdx.x;
    const int lane = tid & 63;
    const int wave = tid >> 6;
    const int wm = wave >> 1;
    const int wn = wave & 1;
    const size_t bm = (size_t)blockIdx.y * 128;
    const size_t bn = (size_t)blockIdx.x * 128;

    f32x4 acc[4][4];
#pragma unroll
    for (int i = 0; i < 4; ++i)
#pragma unroll
        for (int j = 0; j < 4; ++j) acc[i][j] = (f32x4)0.f;

    const int srow = tid >> 2;        // 0..63
    const int scol = (tid & 3) << 3;  // 0,8,16,24
    const u16* Ag = A + (bm + (size_t)srow) * (size_t)lda + scol;
    const u16* Bg = B + (bn + (size_t)srow) * (size_t)K + scol;
    const size_t rA = (size_t)64 * lda;
    const size_t rB = (size_t)64 * K;
    u16* lA0 = &As[tid * 8];
    u16* lA1 = &As[2048 + tid * 8];
    u16* lB0 = &Bs[tid * 8];
    u16* lB1 = &Bs[2048 + tid * 8];

    const int lrow = lane & 15;
    const int lk = (lane >> 4) << 3;

    const int niter = K >> 5;
    for (int t = 0; t < niter; ++t) {
        __syncthreads();
        gl2lds16(Ag, lA0);
        gl2lds16(Ag + rA, lA1);
        gl2lds16(Bg, lB0);
        gl2lds16(Bg + rB, lB1);
        Ag += 32;
        Bg += 32;
        __syncthreads();
        s16x8 af[4], bfr[4];
#pragma unroll
        for (int i = 0; i < 4; ++i)
            af[i] = *(const s16x8*)&As[(wm * 64 + i * 16 + lrow) * 32 + lk];
#pragma unroll
        for (int j = 0; j < 4; ++j)
            bfr[j] = *(const s16x8*)&Bs[(wn * 64 + j * 16 + lrow) * 32 + lk];
#pragma unroll
        for (int i = 0; i < 4; ++i)
#pragma unroll
            for (int j = 0; j < 4; ++j)
                acc[i][j] = __builtin_amdgcn_mfma_f32_16x16x32_bf16(
                    af[i], bfr[j], acc[i][j], 0, 0, 0);
    }

    const size_t crow0 = bm + wm * 64 + ((lane >> 4) << 2);
    const int ccol0 = (int)bn + wn * 64 + (lane & 15);
#pragma unroll
    for (int i = 0; i < 4; ++i) {
#pragma unroll
        for (int j = 0; j < 4; ++j) {
            const int col = ccol0 + j * 16;
            const float bv = bias[col];
            const size_t base = (crow0 + (size_t)i * 16) * (size_t)ldc + col;
#pragma unroll
            for (int r = 0; r < 4; ++r) {
                const float v = acc[i][j][r] + bv;
                if (OUT_BF16)
                    ((u16*)Cout)[base + (size_t)r * ldc] = f2bf(v);
                else
                    ((float*)Cout)[base + (size_t)r * ldc] = v;
            }
        }
    }
}

// ---------------- 256x256 4-window GEMM with read/MFMA overlap --------------
// R5 schedule + row-major mapping, FROZEN (best of 6 variants: 210 µs).
// gemm8_body is shared by gemm8 (plain), gemm8d (two parts in one launch),
// and gemm8m (MEAN epilogue: fused mean-residual write, replaces mean_res).
#define STG_A02(v)                                                            \
    do {                                                                      \
        gl2lds16(aG + (size_t)(v) * 64, &As[(v) & 1][tid * 8]);               \
        gl2lds16(aG + 2 * a64 + (size_t)(v) * 64,                             \
                 &As[(v) & 1][8192 + tid * 8]);                               \
    } while (0)
#define STG_A13(v)                                                            \
    do {                                                                      \
        gl2lds16(aG + a64 + (size_t)(v) * 64, &As[(v) & 1][4096 + tid * 8]);  \
        gl2lds16(aG + 3 * a64 + (size_t)(v) * 64,                             \
                 &As[(v) & 1][12288 + tid * 8]);                              \
    } while (0)
#define STG_B01(v)                                                            \
    do {                                                                      \
        gl2lds16(bG + (size_t)(v) * 64, &Bs[(v) & 1][tid * 8]);               \
        gl2lds16(bG + b64 + (size_t)(v) * 64, &Bs[(v) & 1][4096 + tid * 8]);  \
    } while (0)
#define STG_B23(v)                                                            \
    do {                                                                      \
        gl2lds16(bG + 2 * b64 + (size_t)(v) * 64,                             \
                 &Bs[(v) & 1][8192 + tid * 8]);                               \
        gl2lds16(bG + 3 * b64 + (size_t)(v) * 64,                             \
                 &Bs[(v) & 1][12288 + tid * 8]);                              \
    } while (0)
#define RD_AF(buf, mh, m)                                                     \
    do {                                                                      \
        const u16* p_ = &As[buf][aRow + ((mh) * 64 + (m) * 16) * 64];         \
        aF[m][0] = *(const s16x8*)(p_ + aK0);                                 \
        aF[m][1] = *(const s16x8*)(p_ + aK1);                                 \
    } while (0)
#define RD_B(buf, nh, dst)                                                    \
    do {                                                                      \
        _Pragma("unroll") for (int n_ = 0; n_ < 2; ++n_) {                    \
            const u16* p_ = &Bs[buf][bRow + ((nh) * 32 + n_ * 16) * 64];      \
            dst[n_][0] = *(const s16x8*)(p_ + aK0);                           \
            dst[n_][1] = *(const s16x8*)(p_ + aK1);                           \
        }                                                                     \
    } while (0)
#define MFMA4(ar, bv, ci, cj)                                                 \
    do {                                                                      \
        acc[ci][cj] = __builtin_amdgcn_mfma_f32_16x16x32_bf16(                \
            (ar)[0], (bv)[0], acc[ci][cj], 0, 0, 0);                          \
        acc[ci][cj] = __builtin_amdgcn_mfma_f32_16x16x32_bf16(                \
            (ar)[1], (bv)[1], acc[ci][cj], 0, 0, 0);                          \
    } while (0)

#define TILEW(u, SA13, S2, RDN, V2S, V4S)                                     \
    do {                                                                      \
        const int cur = (u) & 1, oth = cur ^ 1;                               \
        /* w1: quad (0,0) */                                                  \
        if (SA13) STG_A13((u) + 1);                                           \
        RD_B(cur, 1, b1);                                                     \
        __builtin_amdgcn_s_setprio(1);                                        \
        _Pragma("unroll") for (int m = 0; m < 4; ++m) {                       \
            MFMA4(aF[m], b0[0], m, 0);                                        \
            MFMA4(aF[m], b0[1], m, 1);                                        \
        }                                                                     \
        __builtin_amdgcn_s_setprio(0);                                        \
        asm volatile("s_waitcnt " V2S ::: "memory");                          \
        __builtin_amdgcn_s_barrier();                                         \
        /* w2: quad (0,1) + reload aF<-half1(cur) */                          \
        if (S2) STG_A02((u) + 2);                                             \
        __builtin_amdgcn_s_setprio(1);                                        \
        _Pragma("unroll") for (int m = 0; m < 4; ++m) {                       \
            MFMA4(aF[m], b1[0], m, 2);                                        \
            MFMA4(aF[m], b1[1], m, 3);                                        \
            RD_AF(cur, 1, m);                                                 \
        }                                                                     \
        __builtin_amdgcn_s_setprio(0);                                        \
        __builtin_amdgcn_s_barrier();                                         \
        /* w3: quad (1,1) */                                                  \
        if (S2) STG_B01((u) + 2);                                             \
        __builtin_amdgcn_s_setprio(1);                                        \
        _Pragma("unroll") for (int m = 0; m < 4; ++m) {                       \
            MFMA4(aF[m], b1[0], 4 + m, 2);                                    \
            MFMA4(aF[m], b1[1], 4 + m, 3);                                    \
        }                                                                     \
        __builtin_amdgcn_s_setprio(0);                                        \
        asm volatile("s_waitcnt " V4S ::: "memory");                          \
        __builtin_amdgcn_s_barrier();                                         \
        /* w4: quad (1,0) + reload aF<-half0(oth), b0<-oth */                 \
        if (S2) STG_B23((u) + 2);                                             \
        __builtin_amdgcn_s_setprio(1);                                        \
        _Pragma("unroll") for (int m = 0; m < 4; ++m) {                       \
            MFMA4(aF[m], b0[0], 4 + m, 0);                                    \
            MFMA4(aF[m], b0[1], 4 + m, 1);                                    \
            if (RDN) RD_AF(oth, 0, m);                                        \
        }                                                                     \
        __builtin_amdgcn_s_setprio(0);                                        \
        if (RDN) RD_B(oth, 0, b0);                                            \
        __builtin_amdgcn_s_barrier();                                         \
    } while (0)

// MEAN epilogue: instead of writing C rows, write per-sample fused =
// 0.5*((co_r0+co_r1) + (ln_r0+ln_r1)) where co = acc+bias. Fragment rows
// r=0..3 are 4 CONSECUTIVE global rows (C/D layout), so (r0,r1) and (r2,r3)
// are complete samples. Output goes to fout + sample*12288 + col (k-region;
// q-region is this GEMM's still-live A input — writing there would race).
template <bool OUT_BF16, bool MEAN>
__device__ __forceinline__ void gemm8_body(
    const u16* __restrict__ A, int lda, const u16* __restrict__ B,
    const float* __restrict__ bias, void* __restrict__ Cout, int K, int ldc,
    size_t bm, size_t bn, u16 (*As)[16384], u16 (*Bs)[16384],
    const u16* __restrict__ lnp) {
    const int tid = threadIdx.x;
    const int lane = tid & 63;
    const int wave = tid >> 6;
    const int wm = wave >> 2;  // 0..1  (row half, 128 rows)
    const int wn = wave & 3;   // 0..3  (col quarter, 64 cols)

    f32x4 acc[8][4];
#pragma unroll
    for (int i = 0; i < 8; ++i)
#pragma unroll
        for (int j = 0; j < 4; ++j) acc[i][j] = (f32x4)0.f;

    // staging: thread covers row (tid>>3) of each 64-row block, 8 elems at
    // inverse-swizzled global col (rule #21: LDS dest linear).
    const int strow = tid >> 3;
    const int ssw = ((tid & 7) << 3) ^ ((strow & 7) << 3);
    const u16* aG = A + (bm + (size_t)strow) * (size_t)lda + ssw;
    const u16* bG = B + (bn + (size_t)strow) * (size_t)K + ssw;
    const size_t a64 = (size_t)64 * lda;
    const size_t b64 = (size_t)64 * K;

    // fragment read offsets (swizzled)
    const int lrow = lane & 15;
    const int hi8 = (lane >> 4) << 3;  // 0,8,16,24
    const int fswz = (lrow & 7) << 3;
    const int aK0 = hi8 ^ fswz;
    const int aK1 = (32 + hi8) ^ fswz;
    const int aRow = (wm * 128 + lrow) * 64;
    const int bRow = (wn * 64 + lrow) * 64;

    s16x8 aF[4][2], b0[2][2], b1[2][2];

    const int NT = K >> 6;  // K-tiles of 64 (>= 3 required)

    // prologue: tile0 full + tile1 {A02,B01,B23}. vmcnt(6) leaves tile1 trio.
    STG_A02(0);
    STG_A13(0);
    STG_B01(0);
    STG_B23(0);
    STG_A02(1);
    STG_B01(1);
    STG_B23(1);
    asm volatile("s_waitcnt vmcnt(6)" ::: "memory");
    __builtin_amdgcn_s_barrier();
#pragma unroll
    for (int m = 0; m < 4; ++m) RD_AF(0, 0, m);
    RD_B(0, 0, b0);

    for (int u = 0; u < NT - 2; ++u)
        TILEW(u, 1, 1, 1, "vmcnt(8)", "vmcnt(6)");
    TILEW(NT - 2, 1, 0, 1, "vmcnt(8)", "vmcnt(2)");
    TILEW(NT - 1, 0, 0, 0, "vmcnt(0)", "vmcnt(0)");

    // epilogue: C/D layout col=lane&15, row=(lane>>4)*4+reg
    const size_t crow0 = bm + wm * 128 + ((lane >> 4) << 2);
    const int ccol0 = (int)bn + wn * 64 + (lane & 15);
#pragma unroll
    for (int im = 0; im < 8; ++im) {
#pragma unroll
        for (int in = 0; in < 4; ++in) {
            const int col = ccol0 + in * 16;
            const float bv = bias[col];
            if (MEAN) {
                const size_t row = crow0 + (size_t)im * 16;
                const float l0 = bf2f(lnp[row * 2048 + col]);
                const float l1 = bf2f(lnp[(row + 1) * 2048 + col]);
                const float l2 = bf2f(lnp[(row + 2) * 2048 + col]);
                const float l3 = bf2f(lnp[(row + 3) * 2048 + col]);
                const float f0 = 0.5f * (acc[im][in][0] + bv +
                                         acc[im][in][1] + bv + l0 + l1);
                const float f1 = 0.5f * (acc[im][in][2] + bv +
                                         acc[im][in][3] + bv + l2 + l3);
                const size_t s = row >> 1;
                ((u16*)Cout)[s * 12288 + col] = f2bf(f0);
                ((u16*)Cout)[(s + 1) * 12288 + col] = f2bf(f1);
            } else {
                const size_t base =
                    (crow0 + (size_t)im * 16) * (size_t)ldc + col;
#pragma unroll
                for (int r = 0; r < 4; ++r) {
                    const float v = acc[im][in][r] + bv;
                    if (OUT_BF16)
                        ((u16*)Cout)[base + (size_t)r * ldc] = f2bf(v);
                    else
                        ((float*)Cout)[base + (size_t)r * ldc] = v;
                }
            }
        }
    }
}

// bijective XCD swizzle + row-major tile mapping
__device__ __forceinline__ void swz_map(unsigned& bmi, unsigned& bni) {
    const unsigned nwg = gridDim.x * gridDim.y;
    const unsigned orig = blockIdx.y * gridDim.x + blockIdx.x;
    const unsigned q = nwg >> 3, r = nwg & 7u;
    const unsigned xcd = orig & 7u, idx = orig >> 3;
    const unsigned wg =
        (xcd < r ? xcd * (q + 1) : r * (q + 1) + (xcd - r) * q) + idx;
    bmi = wg / gridDim.x;
    bni = wg % gridDim.x;
}

template <bool OUT_BF16>
__global__ __launch_bounds__(512, 2) void gemm8(const u16* __restrict__ A, int lda,
                                                const u16* __restrict__ B,
                                                const float* __restrict__ bias,
                                                void* __restrict__ Cout,
                                                int K, int ldc) {
    __shared__ __align__(16) u16 As[2][16384];
    __shared__ __align__(16) u16 Bs[2][16384];
    unsigned bmi, bni;
    swz_map(bmi, bni);
    gemm8_body<OUT_BF16, false>(A, lda, B, bias, Cout, K, ldc,
                                (size_t)bmi * 256, (size_t)bni * 256, As, Bs,
                                nullptr);
}

// two independent GEMM parts in one launch; part chosen by swizzled bn tile.
template <bool OUT_BF16>
__global__ __launch_bounds__(512, 2) void gemm8d(
    const u16* __restrict__ A0, int lda0, const u16* __restrict__ B0,
    const float* __restrict__ bias0, void* __restrict__ C0, int K0, int nx0,
    const u16* __restrict__ A1, int lda1, const u16* __restrict__ B1,
    const float* __restrict__ bias1, void* __restrict__ C1, int K1, int ldc) {
    __shared__ __align__(16) u16 As[2][16384];
    __shared__ __align__(16) u16 Bs[2][16384];
    unsigned bmi, bni;
    swz_map(bmi, bni);
    if ((int)bni < nx0)
        gemm8_body<OUT_BF16, false>(A0, lda0, B0, bias0, C0, K0, ldc,
                                    (size_t)bmi * 256, (size_t)bni * 256, As,
                                    Bs, nullptr);
    else
        gemm8_body<OUT_BF16, false>(A1, lda1, B1, bias1, C1, K1, ldc,
                                    (size_t)bmi * 256,
                                    (size_t)(bni - nx0) * 256, As, Bs,
                                    nullptr);
}

// GEMM + fused mean-residual epilogue (replaces S7 gemm + S8 mean_res).
__global__ __launch_bounds__(512, 2) void gemm8m(const u16* __restrict__ A,
                                                 int lda,
                                                 const u16* __restrict__ B,
                                                 const float* __restrict__ bias,
                                                 const u16* __restrict__ lnp,
                                                 u16* __restrict__ fout,
                                                 int K) {
    __shared__ __align__(16) u16 As[2][16384];
    __shared__ __align__(16) u16 Bs[2][16384];
    unsigned bmi, bni;
    swz_map(bmi, bni);
    gemm8_body<true, true>(A, lda, B, bias, fout, K, 12288,
                           (size_t)bmi * 256, (size_t)bni * 256, As, Bs, lnp);
}

#undef STG_A02
#undef STG_A13
#undef STG_B01
#undef STG_B23
#undef RD_AF
#undef RD_B
#undef MFMA4
#undef TILEW

// ---------------- tiny attention S=2, IN-PLACE, coalesced -------------------
__device__ __forceinline__ void dot8(uint4 a, uint4 b, float& acc) {
    const unsigned* pa = (const unsigned*)&a;
    const unsigned* pb = (const unsigned*)&b;
#pragma unroll
    for (int i = 0; i < 4; ++i) {
        float alo, ahi, blo, bhi;
        unpack2(pa[i], alo, ahi);
        unpack2(pb[i], blo, bhi);
        acc += alo * blo + ahi * bhi;
    }
}

__global__ __launch_bounds__(256) void attn2(u16* __restrict__ qkv) {
    const int b = (blockIdx.x * 256 + threadIdx.x) >> 6;  // sample = global wave
    const int l = threadIdx.x & 63;
    u16* t0 = qkv + (size_t)(2 * b) * 6144;
    u16* t1 = t0 + 6144;
    const float scale = 0.0883883476483184f;  // 1/sqrt(128)
#pragma unroll
    for (int hg = 0; hg < 4; ++hg) {
        const int o = hg * 512 + l * 8;
        const uint4 q0 = *(const uint4*)(t0 + o);
        const uint4 q1 = *(const uint4*)(t1 + o);
        const uint4 k0 = *(const uint4*)(t0 + 2048 + o);
        const uint4 k1 = *(const uint4*)(t1 + 2048 + o);
        float s00 = 0.f, s01 = 0.f, s10 = 0.f, s11 = 0.f;
        dot8(q0, k0, s00);
        dot8(q0, k1, s01);
        dot8(q1, k0, s10);
        dot8(q1, k1, s11);
#pragma unroll
        for (int m = 1; m < 16; m <<= 1) {
            s00 += __shfl_xor(s00, m);
            s01 += __shfl_xor(s01, m);
            s10 += __shfl_xor(s10, m);
            s11 += __shfl_xor(s11, m);
        }
        s00 *= scale; s01 *= scale; s10 *= scale; s11 *= scale;
        const float m0 = fmaxf(s00, s01), m1 = fmaxf(s10, s11);
        const float e00 = __expf(s00 - m0), e01 = __expf(s01 - m0);
        const float e10 = __expf(s10 - m1), e11 = __expf(s11 - m1);
        const float r0 = 1.f / (e00 + e01), r1 = 1.f / (e10 + e11);
        const float p00 = e00 * r0, p01 = e01 * r0;
        const float p10 = e10 * r1, p11 = e11 * r1;
        const uint4 v0 = *(const uint4*)(t0 + 4096 + o);
        const uint4 v1 = *(const uint4*)(t1 + 4096 + o);
        const unsigned* pv0 = (const unsigned*)&v0;
        const unsigned* pv1 = (const unsigned*)&v1;
        uint4 c0v, c1v;
        unsigned* pc0 = (unsigned*)&c0v;
        unsigned* pc1 = (unsigned*)&c1v;
#pragma unroll
        for (int i = 0; i < 4; ++i) {
            float alo, ahi, blo, bhi;
            unpack2(pv0[i], alo, ahi);
            unpack2(pv1[i], blo, bhi);
            pc0[i] = pack2(p00 * alo + p01 * blo, p00 * ahi + p01 * bhi);
            pc1[i] = pack2(p10 * alo + p11 * blo, p10 * ahi + p11 * bhi);
        }
        *(uint4*)(t0 + o) = c0v;  // ctx token0 -> q-region
        *(uint4*)(t1 + o) = c1v;  // ctx token1 -> q-region
    }
}

// ---------------- LayerNorm C=2048 (bf16 in strided / out dense) ------------
__global__ __launch_bounds__(256) void ln_k(const u16* __restrict__ x, int ldx,
                                            const float* __restrict__ w,
                                            const float* __restrict__ bb,
                                            u16* __restrict__ y) {
    __shared__ float red[8];
    const int row = blockIdx.x;
    const int tid = threadIdx.x;
    const uint4 v = ((const uint4*)(x + (size_t)row * ldx))[tid];
    const unsigned* pw = (const unsigned*)&v;
    float f[8];
#pragma unroll
    for (int i = 0; i < 4; ++i) unpack2(pw[i], f[2 * i], f[2 * i + 1]);
    float s = 0.f, q = 0.f;
#pragma unroll
    for (int i = 0; i < 8; ++i) {
        s += f[i];
        q += f[i] * f[i];
    }
#pragma unroll
    for (int off = 32; off > 0; off >>= 1) {
        s += __shfl_down(s, off);
        q += __shfl_down(q, off);
    }
    if ((tid & 63) == 0) {
        red[tid >> 6] = s;
        red[4 + (tid >> 6)] = q;
    }
    __syncthreads();
    s = red[0] + red[1] + red[2] + red[3];
    q = red[4] + red[5] + red[6] + red[7];
    const float mu = s * (1.f / 2048.f);
    const float var = q * (1.f / 2048.f) - mu * mu;
    const float rstd = rsqrtf(var + 1e-5f);
    const float4 w0 = ((const float4*)w)[2 * tid];
    const float4 w1 = ((const float4*)w)[2 * tid + 1];
    const float4 b0 = ((const float4*)bb)[2 * tid];
    const float4 b1 = ((const float4*)bb)[2 * tid + 1];
    const float wv[8] = {w0.x, w0.y, w0.z, w0.w, w1.x, w1.y, w1.z, w1.w};
    const float bv[8] = {b0.x, b0.y, b0.z, b0.w, b1.x, b1.y, b1.z, b1.w};
    uint4 o;
    unsigned* po = (unsigned*)&o;
#pragma unroll
    for (int i = 0; i < 4; ++i) {
        float lo = (f[2 * i] - mu) * rstd * wv[2 * i] + bv[2 * i];
        float hi = (f[2 * i + 1] - mu) * rstd * wv[2 * i + 1] + bv[2 * i + 1];
        po[i] = pack2(lo, hi);
    }
    ((uint4*)(y + (size_t)row * 2048))[tid] = o;
}

extern "C" void kernel_launch(void* const* d_in, const int* in_sizes, int n_in,
                              void* d_out, int out_size, void* d_ws, size_t ws_size,
                              hipStream_t stream) {
    (void)in_sizes; (void)n_in; (void)out_size;
    const float* text   = (const float*)d_in[0];
    const float* graph  = (const float*)d_in[1];
    const float* Wt     = (const float*)d_in[2];
    const float* bt     = (const float*)d_in[3];
    const float* Wg     = (const float*)d_in[4];
    const float* bg     = (const float*)d_in[5];
    const float* Wqkv_s = (const float*)d_in[6];
    const float* bqkv_s = (const float*)d_in[7];
    const float* Wo_s   = (const float*)d_in[8];
    const float* bo_s   = (const float*)d_in[9];
    const float* Wqkv_c = (const float*)d_in[10];
    const float* bqkv_c = (const float*)d_in[11];
    const float* Wo_c   = (const float*)d_in[12];
    const float* bo_c   = (const float*)d_in[13];
    const float* ln_w   = (const float*)d_in[14];
    const float* ln_b   = (const float*)d_in[15];
    const float* Wout   = (const float*)d_in[16];
    const float* bout   = (const float*)d_in[17];
    float* out = (float*)d_out;

    // ---- weight area: 80 MiB of bf16 casts at base of ws (cast_w7 order) ----
    char* ws = (char*)d_ws;
    u16* wQs  = (u16*)ws;                          // 12,582,912 elems
    u16* wQc  = wQs + 12582912ull;
    u16* wOs  = wQc + 12582912ull;                 // 4,194,304
    u16* wOc  = wOs + 4194304ull;
    u16* wWt  = wOc + 4194304ull;                  // 4,194,304
    u16* wWg  = wWt + 4194304ull;                  // 2,097,152
    u16* wOut = wWg + 2097152ull;                  // 2,097,152
    const size_t WB = 83886080ull;                 // 80 MiB weight area

    // ---- chunk size: per-sample scratch = stacked 8KB + ln 8KB + qkv 24KB ----
    size_t CH = 8192;
    while (CH > 256 && WB + 40960ull * CH > ws_size) CH >>= 1;
    fprintf(stderr, "[kernel_launch] ws_size=%zu need=%zu CH=%zu\n",
            ws_size, WB + 40960ull * CH, CH);
    if (WB + 40960ull * CH > ws_size || d_ws == nullptr) return;

    const size_t T = 2 * CH;
    char* ca = ws + WB;                            // chunk area
    u16* stacked_c = (u16*)ca;                     // T*2048 elems, dense
    u16* ln_c      = (u16*)(ca + 4096 * T);        // T*2048 elems, dense
    u16* qkv_c     = (u16*)(ca + 8192 * T);        // T*6144 elems, stride 6144
    // input-cast staging reuses qkv_c (dead until S3 writes it)
    u16* tb_c = qkv_c;                             // CH*2048 bf16 text chunk
    u16* gb_c = qkv_c + (size_t)CH * 2048;         // CH*1024 bf16 graph chunk

    // ---- one-time fused weight cast (single launch) ----
    cast_w7<<<40960, 256, 0, stream>>>(Wqkv_s, Wqkv_c, Wo_s, Wo_c, Wt, Wg,
                                       Wout, wQs);

    const dim3 blk(256);
    const dim3 blk8(512);
    const unsigned gy  = (unsigned)(CH / 128);
    const unsigned gy8 = (unsigned)(CH / 256);     // 256-row tiles over CH rows
    const unsigned g8  = (unsigned)(T / 256);      // 256-row tiles over T tokens

    for (size_t c0 = 0; c0 < 8192; c0 += CH) {
        // S1: cast input chunks to bf16 (into dead qkv_c region), one launch
        {
            const int nt4 = (int)(CH * 512);
            const int ng4 = (int)(CH * 256);
            cast_in<<<(unsigned)((nt4 + ng4 + 255) / 256), blk, 0, stream>>>(
                text + c0 * 2048, graph + c0 * 1024, tb_c, gb_c, nt4, ng4);
        }
        // S2: both projections in ONE launch (text: 8 bn-tiles K=2048;
        //     graph: 8 bn-tiles K=1024) -> interleaved stacked
        gemm8d<true><<<dim3(16, gy8), blk8, 0, stream>>>(
            tb_c, 2048, wWt, bt, stacked_c, 2048, 8,
            gb_c, 1024, wWg, bg, stacked_c + 2048, 1024, 4096);
        // S3: self QKV -> qkv (ldc 6144), then in-place attention
        gemm8<true><<<dim3(24, g8), blk8, 0, stream>>>(
            stacked_c, 2048, wQs, bqkv_s, qkv_c, 2048, 6144);
        attn2<<<(unsigned)(CH / 4), blk, 0, stream>>>(qkv_c);
        // S4: self Wo: A=ctx (q-region, lda 6144) -> ao (v-region, ldc 6144)
        gemm8<true><<<dim3(8, g8), blk8, 0, stream>>>(
            qkv_c, 6144, wOs, bo_s, qkv_c + 4096, 2048, 6144);
        // S5: LayerNorm: ao (stride 6144) -> ln dense
        ln_k<<<(unsigned)T, blk, 0, stream>>>(qkv_c + 4096, 6144, ln_w, ln_b, ln_c);
        // S6: cross QKV in ONE launch (Q from ln: 8 tiles; K/V from stacked:
        //     16 tiles) -> q / k,v regions
        gemm8d<true><<<dim3(24, g8), blk8, 0, stream>>>(
            ln_c, 2048, wQc, bqkv_c, qkv_c, 2048, 8,
            stacked_c, 2048, wQc + 2048ull * 2048, bqkv_c + 2048,
            qkv_c + 2048, 2048, 6144);
        attn2<<<(unsigned)(CH / 4), blk, 0, stream>>>(qkv_c);
        // S7+S8 fused: cross Wo (A=ctx', q-region) with mean-residual
        // epilogue -> fused written to k-region (sample stride 12288).
        // q-region is still being read as A by other blocks; k-region is
        // dead after attn2#2 -> race-free.
        gemm8m<<<dim3(8, g8), blk8, 0, stream>>>(
            qkv_c, 6144, wOc, bo_c, ln_c, qkv_c + 2048, 2048);
        // S9: final projection: A=fused (k-region, lda 12288) -> d_out fp32
        gemm_async<false><<<dim3(8, gy), blk, 0, stream>>>(
            qkv_c + 2048, 12288, wOut, bout, out + c0 * 1024, 2048, 1024);
    }
}